// Round 8
// baseline (379.583 us; speedup 1.0000x reference)
//
#include <hip/hip_runtime.h>

// 2-layer LSTM (H=64) encode(128) + AR(60), B=4096.
// 512 blocks x 256 threads, M=8 real batch elements per block -> 2 independent
// blocks per CU. Waves from different blocks have INDEPENDENT barriers, so one
// block's latency/barrier chain is filled by the other block's issue stream
// (R2/R7 showed same-barrier duplication never helps; R5/R6 showed 1024-thread
// blocks spill). MFMA rows 8..15 are zero-padding (bounded garbage, never stored).
// Retimed body: encode iter t computes L1(t) and L0(t+1) (independent -> 2 ILP
// chains/wave), 1 barrier; AR: 2 barriers/step, pred folded via Wx = Wih0@Wfc.
// Register diet: ONE BW0 array rebuilt in place at AR start (R7: 128 VGPRs).

#define T_ENC 128
#define D_IN 4
#define H 64
#define STEPS 60
#define MR 8      // real elements per block
#define A0S 104   // halves/row: [x(4) | h0(64) | zero-pad]
#define A1S 136   // halves/row: [h0(64) | h1(64)] + slack
#define XN (MR * T_ENC * D_IN)   // 4096 halves
#define NT 256

typedef _Float16 half8 __attribute__((ext_vector_type(8)));
typedef _Float16 half4_t __attribute__((ext_vector_type(4)));
typedef float float4v __attribute__((ext_vector_type(4)));

__device__ __forceinline__ float fast_sigmoid(float x) {
    float e = __builtin_amdgcn_exp2f(-1.44269504f * x);
    return __builtin_amdgcn_rcpf(1.0f + e);
}
__device__ __forceinline__ float fast_tanh(float x) {
    float e = __builtin_amdgcn_exp2f(2.88539008f * x);   // exp(2x)
    return __builtin_fmaf(-2.0f, __builtin_amdgcn_rcpf(e + 1.0f), 1.0f);
}

__global__ __launch_bounds__(NT, 2) void lstm_ar_kernel(
    const float* __restrict__ x,
    const float* __restrict__ Wih0, const float* __restrict__ Whh0,
    const float* __restrict__ bih0, const float* __restrict__ bhh0,
    const float* __restrict__ Wih1, const float* __restrict__ Whh1,
    const float* __restrict__ bih1, const float* __restrict__ bhh1,
    const float* __restrict__ Wfc,  const float* __restrict__ bfc,
    float* __restrict__ out)
{
    __shared__ __align__(16) _Float16 A0buf[2][16 * A0S];
    __shared__ __align__(16) _Float16 A1buf[2][16 * A1S];
    __shared__ __align__(16) _Float16 xAll[XN];            // [elem][t][d] fp16
    __shared__ __align__(16) float    predsS[MR * STEPS * D_IN];

    const int tid  = threadIdx.x;
    const int wave = tid >> 6;
    const int lane = tid & 63;
    const int n16  = lane & 15;
    const int quad = lane >> 4;
    const int m0   = blockIdx.x * MR;
    const int m    = n16;             // A-frag row
    const int jcol = 16 * wave + n16; // hidden column owned in epilogues

    { _Float16* z = &A0buf[0][0]; for (int i = tid; i < 2 * 16 * A0S; i += NT) z[i] = (_Float16)0.f; }
    { _Float16* z = &A1buf[0][0]; for (int i = tid; i < 2 * 16 * A1S; i += NT) z[i] = (_Float16)0.f; }
    for (int j = tid; j < XN / 4; j += NT) {
        const float4v v = *(const float4v*)&x[(size_t)m0 * T_ENC * D_IN + (size_t)j * 4];
        *(half4_t*)&xAll[j * 4] =
            (half4_t){(_Float16)v[0], (_Float16)v[1], (_Float16)v[2], (_Float16)v[3]};
    }

    // ---- weight B-fragments (fp16): B[k][n], n = 16*(wave + 4*tau) + n16 ----
    half8 B1f[4][4];    // layer1: K=128 = [h0 | h1]
    half8 BW0[4][4];    // encode: [x(4);h0(64);pad] kt0..2 (kt3 zero); AR: [Whh0 | Wx]
    float b1v[4], b0v[4], b0arv[4];
    #pragma unroll
    for (int tau = 0; tau < 4; ++tau) {
        const int n = 16 * (wave + 4 * tau) + n16;
        b1v[tau] = bih1[n] + bhh1[n];
        b0v[tau] = bih0[n] + bhh0[n];
        float wb = 0.f;
        #pragma unroll
        for (int d = 0; d < 4; ++d) wb += Wih0[n * D_IN + d] * bfc[d];
        b0arv[tau] = b0v[tau] + wb;
        #pragma unroll
        for (int kt = 0; kt < 4; ++kt)
            #pragma unroll
            for (int j = 0; j < 8; ++j) {
                const int k = kt * 32 + quad * 8 + j;
                B1f[kt][tau][j] = (_Float16)((k < H) ? Wih1[n * H + k] : Whh1[n * H + (k - H)]);
                float v = 0.f;
                if (k < 4)       v = Wih0[n * D_IN + k];
                else if (k < 68) v = Whh0[n * H + (k - 4)];
                BW0[kt][tau][j] = (_Float16)v;
            }
    }
    // head fragments (wave 0)
    half8 Bfc[2];
    float bfcv = 0.f;
    if (wave == 0) {
        #pragma unroll
        for (int kt = 0; kt < 2; ++kt)
            #pragma unroll
            for (int j = 0; j < 8; ++j) {
                const int k = kt * 32 + quad * 8 + j;
                Bfc[kt][j] = (_Float16)((n16 < 4) ? Wfc[n16 * H + k] : 0.f);
            }
        if (n16 < 4) bfcv = bfc[n16];
    }

    float c0s[4] = {0.f, 0.f, 0.f, 0.f};
    float c1s[4] = {0.f, 0.f, 0.f, 0.f};

    __syncthreads();   // LDS zero + xAll ready

    // x(0) -> A0buf[1] x-slot (prologue); x(1) -> A0buf[0] (iter-0 input)
    if (wave == 2 && lane < MR) {
        *(half4_t*)&A0buf[1][lane * A0S] = *(const half4_t*)&xAll[(lane * T_ENC + 0) * D_IN];
        *(half4_t*)&A0buf[0][lane * A0S] = *(const half4_t*)&xAll[(lane * T_ENC + 1) * D_IN];
    }
    __syncthreads();

    // ---- prologue: L0 step 0 ----
    {
        half8 a0f[3];
        #pragma unroll
        for (int kt = 0; kt < 3; ++kt)
            a0f[kt] = *(const half8*)&A0buf[1][m * A0S + kt * 32 + quad * 8];
        float4v C0[4];
        #pragma unroll
        for (int tau = 0; tau < 4; ++tau)
            C0[tau] = (float4v){b0v[tau], b0v[tau], b0v[tau], b0v[tau]};
        #pragma unroll
        for (int kt = 0; kt < 3; ++kt)
            #pragma unroll
            for (int tau = 0; tau < 4; ++tau)
                C0[tau] = __builtin_amdgcn_mfma_f32_16x16x32_f16(a0f[kt], BW0[kt][tau], C0[tau], 0, 0, 0);
        #pragma unroll
        for (int r = 0; r < 4; ++r) {
            const float ig = fast_sigmoid(C0[0][r]);
            const float fg = fast_sigmoid(C0[1][r]);
            const float gg = fast_tanh   (C0[2][r]);
            const float og = fast_sigmoid(C0[3][r]);
            const float c  = fg * c0s[r] + ig * gg;
            c0s[r] = c;
            const _Float16 hh = (_Float16)(og * fast_tanh(c));
            const int row = quad * 4 + r;
            A1buf[0][row * A1S + jcol]     = hh;
            A0buf[0][row * A0S + 4 + jcol] = hh;
        }
    }
    __syncthreads();

    // ---- encode: iter t = L1(t) and L0(t+1) on every wave; 1 barrier ----
    for (int t = 0; t < T_ENC; ++t) {
        const int p = t & 1;
        const _Float16* cur0 = &A0buf[p][0];
        const _Float16* cur1 = &A1buf[p][0];
        _Float16* nxt0 = &A0buf[1 - p][0];
        _Float16* nxt1 = &A1buf[1 - p][0];

        half8 a1f[4], a0f[3];
        #pragma unroll
        for (int kt = 0; kt < 4; ++kt)
            a1f[kt] = *(const half8*)&cur1[m * A1S + kt * 32 + quad * 8];
        #pragma unroll
        for (int kt = 0; kt < 3; ++kt)
            a0f[kt] = *(const half8*)&cur0[m * A0S + kt * 32 + quad * 8];

        float4v C1[4], C0[4];
        #pragma unroll
        for (int tau = 0; tau < 4; ++tau) {
            C1[tau] = (float4v){b1v[tau], b1v[tau], b1v[tau], b1v[tau]};
            C0[tau] = (float4v){b0v[tau], b0v[tau], b0v[tau], b0v[tau]};
        }
        #pragma unroll
        for (int kt = 0; kt < 4; ++kt)
            #pragma unroll
            for (int tau = 0; tau < 4; ++tau)
                C1[tau] = __builtin_amdgcn_mfma_f32_16x16x32_f16(a1f[kt], B1f[kt][tau], C1[tau], 0, 0, 0);
        #pragma unroll
        for (int kt = 0; kt < 3; ++kt)
            #pragma unroll
            for (int tau = 0; tau < 4; ++tau)
                C0[tau] = __builtin_amdgcn_mfma_f32_16x16x32_f16(a0f[kt], BW0[kt][tau], C0[tau], 0, 0, 0);

        // epi1: layer1(t) -> h1(t)
        #pragma unroll
        for (int r = 0; r < 4; ++r) {
            const float ig = fast_sigmoid(C1[0][r]);
            const float fg = fast_sigmoid(C1[1][r]);
            const float gg = fast_tanh   (C1[2][r]);
            const float og = fast_sigmoid(C1[3][r]);
            const float c  = fg * c1s[r] + ig * gg;
            c1s[r] = c;
            nxt1[(quad * 4 + r) * A1S + 64 + jcol] = (_Float16)(og * fast_tanh(c));
        }
        // epi0: layer0(t+1) -> h0(t+1)
        #pragma unroll
        for (int r = 0; r < 4; ++r) {
            const float ig = fast_sigmoid(C0[0][r]);
            const float fg = fast_sigmoid(C0[1][r]);
            const float gg = fast_tanh   (C0[2][r]);
            const float og = fast_sigmoid(C0[3][r]);
            const float c  = fg * c0s[r] + ig * gg;
            c0s[r] = c;
            const _Float16 hh = (_Float16)(og * fast_tanh(c));
            const int row = quad * 4 + r;
            nxt1[row * A1S + jcol]     = hh;
            nxt0[row * A0S + 4 + jcol] = hh;
        }
        if (wave == 2 && lane < MR) {   // x(t+2) -> nxt0 x-slot
            int tn = t + 2; if (tn > T_ENC - 1) tn = T_ENC - 1;
            *(half4_t*)&nxt0[lane * A0S] = *(const half4_t*)&xAll[(lane * T_ENC + tn) * D_IN];
        }
        __syncthreads();
    }

    // ---- AR prep: overwrite BW0 in place -> [Whh0 | Wx = Wih0@Wfc] ----
    #pragma unroll
    for (int tau = 0; tau < 4; ++tau) {
        const int n = 16 * (wave + 4 * tau) + n16;
        #pragma unroll
        for (int kt = 0; kt < 4; ++kt)
            #pragma unroll
            for (int j = 0; j < 8; ++j) {
                const int k = kt * 32 + quad * 8 + j;
                float v;
                if (k < H) v = Whh0[n * H + k];
                else {
                    const int c = k - H;
                    v = Wih0[n * D_IN + 0] * Wfc[0 * H + c] + Wih0[n * D_IN + 1] * Wfc[1 * H + c]
                      + Wih0[n * D_IN + 2] * Wfc[2 * H + c] + Wih0[n * D_IN + 3] * Wfc[3 * H + c];
                }
                BW0[kt][tau][j] = (_Float16)v;
            }
    }

    // ---- AR: phase1 = L1 over [h0(s)|h1(s-1)] -> h1(s); barrier;
    //          phase2 = L0ar over [h0(s)|h1(s)] -> h0(s+1), head on wave0; barrier ----
    for (int s = 0; s < STEPS; ++s) {
        const int q = s & 1;
        const _Float16* cur = &A1buf[q][0];
        _Float16* nxt = &A1buf[1 - q][0];

        half8 a1f[4];
        #pragma unroll
        for (int kt = 0; kt < 4; ++kt)
            a1f[kt] = *(const half8*)&cur[m * A1S + kt * 32 + quad * 8];
        float4v C1[4];
        #pragma unroll
        for (int tau = 0; tau < 4; ++tau)
            C1[tau] = (float4v){b1v[tau], b1v[tau], b1v[tau], b1v[tau]};
        #pragma unroll
        for (int kt = 0; kt < 4; ++kt)
            #pragma unroll
            for (int tau = 0; tau < 4; ++tau)
                C1[tau] = __builtin_amdgcn_mfma_f32_16x16x32_f16(a1f[kt], B1f[kt][tau], C1[tau], 0, 0, 0);
        #pragma unroll
        for (int r = 0; r < 4; ++r) {
            const float ig = fast_sigmoid(C1[0][r]);
            const float fg = fast_sigmoid(C1[1][r]);
            const float gg = fast_tanh   (C1[2][r]);
            const float og = fast_sigmoid(C1[3][r]);
            const float c  = fg * c1s[r] + ig * gg;
            c1s[r] = c;
            nxt[(quad * 4 + r) * A1S + 64 + jcol] = (_Float16)(og * fast_tanh(c));
        }
        __syncthreads();   // h1(s) visible

        half8 aA[4];
        #pragma unroll
        for (int kt = 0; kt < 2; ++kt)
            aA[kt] = *(const half8*)&cur[m * A1S + kt * 32 + quad * 8];            // h0(s)
        #pragma unroll
        for (int kt = 0; kt < 2; ++kt)
            aA[2 + kt] = *(const half8*)&nxt[m * A1S + 64 + kt * 32 + quad * 8];   // h1(s)
        float4v C0[4];
        #pragma unroll
        for (int tau = 0; tau < 4; ++tau)
            C0[tau] = (float4v){b0arv[tau], b0arv[tau], b0arv[tau], b0arv[tau]};
        #pragma unroll
        for (int kt = 0; kt < 4; ++kt)
            #pragma unroll
            for (int tau = 0; tau < 4; ++tau)
                C0[tau] = __builtin_amdgcn_mfma_f32_16x16x32_f16(aA[kt], BW0[kt][tau], C0[tau], 0, 0, 0);

        if (wave == 0) {   // head: pred(s) = Wfc·h1(s)+bfc (output only)
            float4v Cp = (float4v){bfcv, bfcv, bfcv, bfcv};
            Cp = __builtin_amdgcn_mfma_f32_16x16x32_f16(aA[2], Bfc[0], Cp, 0, 0, 0);
            Cp = __builtin_amdgcn_mfma_f32_16x16x32_f16(aA[3], Bfc[1], Cp, 0, 0, 0);
            if (n16 < 4 && quad < MR / 4) {   // rows 0..7 only
                #pragma unroll
                for (int r = 0; r < 4; ++r)
                    predsS[(quad * 4 + r) * (STEPS * D_IN) + s * D_IN + n16] = Cp[r];
            }
        }

        #pragma unroll
        for (int r = 0; r < 4; ++r) {
            const float ig = fast_sigmoid(C0[0][r]);
            const float fg = fast_sigmoid(C0[1][r]);
            const float gg = fast_tanh   (C0[2][r]);
            const float og = fast_sigmoid(C0[3][r]);
            const float c  = fg * c0s[r] + ig * gg;
            c0s[r] = c;
            nxt[(quad * 4 + r) * A1S + jcol] = (_Float16)(og * fast_tanh(c));
        }
        __syncthreads();   // h0(s+1) visible
    }

    // ---- bulk store preds (MR*STEPS float4s) ----
    for (int j = tid; j < MR * STEPS; j += NT) {
        const int elem = j / STEPS, r = j - elem * STEPS;
        ((float4v*)out)[(size_t)(m0 + elem) * STEPS + r] = ((const float4v*)predsS)[j];
    }
}

extern "C" void kernel_launch(void* const* d_in, const int* in_sizes, int n_in,
                              void* d_out, int out_size, void* d_ws, size_t ws_size,
                              hipStream_t stream) {
    const float* x    = (const float*)d_in[0];
    const float* Wih0 = (const float*)d_in[1];
    const float* Whh0 = (const float*)d_in[2];
    const float* bih0 = (const float*)d_in[3];
    const float* bhh0 = (const float*)d_in[4];
    const float* Wih1 = (const float*)d_in[5];
    const float* Whh1 = (const float*)d_in[6];
    const float* bih1 = (const float*)d_in[7];
    const float* bhh1 = (const float*)d_in[8];
    const float* Wfc  = (const float*)d_in[9];
    const float* bfc  = (const float*)d_in[10];
    float* out = (float*)d_out;

    dim3 grid(4096 / MR);  // 512 blocks -> 2 independent blocks per CU
    dim3 block(NT);        // 4 waves
    lstm_ar_kernel<<<grid, block, 0, stream>>>(
        x, Wih0, Whh0, bih0, bhh0, Wih1, Whh1, bih1, bhh1, Wfc, bfc, out);
}

// Round 9
// 311.609 us; speedup vs baseline: 1.2181x; 1.2181x over previous
//
#include <hip/hip_runtime.h>

// 2-layer LSTM (H=64) encode(128) + AR(60), B=4096, persistent per-block.
// 256 blocks x 512 threads. BARRIER-FREE main loop: waves 0-3 (grp0) own layer1,
// waves 4-7 (grp1) own layer0; sync via monotone LDS counters + ring buffers
// instead of __syncthreads (248 block-wide barrier convergences was ~50% dead
// time at R4's 2100-cyc intervals). grp1 runs up to 2 steps ahead in encode.
// AR: L0 folded as Whh0*h0 + (Wih0@Wfc)*h1 -> pred off the dataflow; head on
// grp1-w4==0 reusing its h1 A-frags. Unified step index t=0..187:
//   t<=128: h0(t)=L0(x(min(t,127)), h0(t-1));  t>=129: h0(t)=Whh0*h0(t-1)+Wx*h1(t-1)
//   h1(t)=L1(h0(t), h1(t-1));  pred(s)=Wfc*h1(128+s)+bfc, s=0..59.

#define T_ENC 128
#define D_IN 4
#define H 64
#define STEPS 60
#define M 16
#define TT 188
#define SROW 72                  // halves per ring row (16B-aligned frag reads)
#define SLOT (M * SROW)          // 1152 halves per ring slot
#define NT 512

typedef _Float16 half8 __attribute__((ext_vector_type(8)));
typedef _Float16 half4_t __attribute__((ext_vector_type(4)));
typedef float float4v __attribute__((ext_vector_type(4)));

__device__ __forceinline__ float fast_sigmoid(float x) {
    float e = __builtin_amdgcn_exp2f(-1.44269504f * x);
    return __builtin_amdgcn_rcpf(1.0f + e);
}
__device__ __forceinline__ float fast_tanh(float x) {
    float e = __builtin_amdgcn_exp2f(2.88539008f * x);   // exp(2x)
    return __builtin_fmaf(-2.0f, __builtin_amdgcn_rcpf(e + 1.0f), 1.0f);
}
__device__ __forceinline__ void waitCtr(volatile int* c, int target) {
    if (target <= 0) return;
    int g = 0;
    while (*c < target && ++g < (1 << 24)) { }
    __threadfence_block();   // order: poll -> subsequent LDS data reads
}

__global__ __launch_bounds__(NT, 2) void lstm_ar_kernel(
    const float* __restrict__ x,
    const float* __restrict__ Wih0, const float* __restrict__ Whh0,
    const float* __restrict__ bih0, const float* __restrict__ bhh0,
    const float* __restrict__ Wih1, const float* __restrict__ Whh1,
    const float* __restrict__ bih1, const float* __restrict__ bhh1,
    const float* __restrict__ Wfc,  const float* __restrict__ bfc,
    float* __restrict__ out)
{
    __shared__ __align__(16) _Float16 h0r[4 * SLOT];       // h0(t) ring, depth 4
    __shared__ __align__(16) _Float16 h1r[3 * SLOT];       // h1(t) ring, depth 3
    __shared__ __align__(16) _Float16 xAll[M * T_ENC * D_IN];
    __shared__ __align__(16) float    predsS[M * STEPS * D_IN];
    __shared__ int ctr_h0, ctr_h1;                         // monotone: 4*(steps done)

    const int tid  = threadIdx.x;
    const int wave = tid >> 6;
    const int lane = tid & 63;
    const int n16  = lane & 15;
    const int quad = lane >> 4;
    const int grp  = wave >> 2;        // 0: layer1, 1: layer0(+head)
    const int w4   = wave & 3;
    const int m0   = blockIdx.x * M;
    const int m    = n16;              // A-frag row (batch element)
    const int jcol = 16 * w4 + n16;    // hidden column owned in epilogue

    { _Float16* z = &h0r[0]; for (int i = tid; i < 4 * SLOT; i += NT) z[i] = (_Float16)0.f; }
    { _Float16* z = &h1r[0]; for (int i = tid; i < 3 * SLOT; i += NT) z[i] = (_Float16)0.f; }
    for (int j = tid; j < M * T_ENC * D_IN / 4; j += NT) {
        const float4v v = *(const float4v*)&x[(size_t)m0 * T_ENC * D_IN + (size_t)j * 4];
        *(half4_t*)&xAll[j * 4] =
            (half4_t){(_Float16)v[0], (_Float16)v[1], (_Float16)v[2], (_Float16)v[3]};
    }
    if (tid == 0) { ctr_h0 = 0; ctr_h1 = 0; }

    // ---- weights (B-frag layout: n = 16*(w4+4*tau)+n16, k = kt*32+quad*8+j) ----
    half8 B1f[4][4];                  // grp0: L1, K=128 = [h0 | h1]
    half8 BWhh0[2][4], Bx[4], Wxf[2][4], BfcF[2];   // grp1
    float bias_a[4], bias_b[4];       // grp0: b1 (a only); grp1: enc b0 (a), AR b0+Wih0·bfc (b)
    float bfcv = 0.f;
    if (grp == 0) {
        #pragma unroll
        for (int tau = 0; tau < 4; ++tau) {
            const int n = 16 * (w4 + 4 * tau) + n16;
            bias_a[tau] = bih1[n] + bhh1[n];
            #pragma unroll
            for (int kt = 0; kt < 4; ++kt)
                #pragma unroll
                for (int j = 0; j < 8; ++j) {
                    const int k = kt * 32 + quad * 8 + j;
                    B1f[kt][tau][j] = (_Float16)((k < H) ? Wih1[n * H + k] : Whh1[n * H + (k - H)]);
                }
        }
    } else {
        #pragma unroll
        for (int tau = 0; tau < 4; ++tau) {
            const int n = 16 * (w4 + 4 * tau) + n16;
            bias_a[tau] = bih0[n] + bhh0[n];
            float wb = 0.f;
            #pragma unroll
            for (int d = 0; d < 4; ++d) wb += Wih0[n * D_IN + d] * bfc[d];
            bias_b[tau] = bias_a[tau] + wb;
            #pragma unroll
            for (int kt = 0; kt < 2; ++kt)
                #pragma unroll
                for (int j = 0; j < 8; ++j) {
                    const int k = kt * 32 + quad * 8 + j;
                    BWhh0[kt][tau][j] = (_Float16)Whh0[n * H + k];
                    float wx = Wih0[n * D_IN + 0] * Wfc[0 * H + k] + Wih0[n * D_IN + 1] * Wfc[1 * H + k]
                             + Wih0[n * D_IN + 2] * Wfc[2 * H + k] + Wih0[n * D_IN + 3] * Wfc[3 * H + k];
                    Wxf[kt][tau][j] = (_Float16)wx;
                }
            #pragma unroll
            for (int j = 0; j < 8; ++j) {
                const int k = quad * 8 + j;
                Bx[tau][j] = (_Float16)((k < D_IN) ? Wih0[n * D_IN + k] : 0.f);
            }
        }
        if (w4 == 0) {
            #pragma unroll
            for (int kt = 0; kt < 2; ++kt)
                #pragma unroll
                for (int j = 0; j < 8; ++j) {
                    const int k = kt * 32 + quad * 8 + j;
                    BfcF[kt][j] = (_Float16)((n16 < 4) ? Wfc[n16 * H + k] : 0.f);
                }
            if (n16 < 4) bfcv = bfc[n16];
        }
    }

    __syncthreads();   // init complete (only barrier before the end)

    if (grp == 0) {
        // ================= layer-1 group =================
        float c1s[4] = {0.f, 0.f, 0.f, 0.f};
        for (int t = 0; t < TT; ++t) {
            waitCtr(&ctr_h0, 4 * (t + 1));                       // h0(t) ready
            const _Float16* h0s = &h0r[(t & 3) * SLOT];
            const _Float16* h1s = &h1r[((t + 2) % 3) * SLOT];    // slot of h1(t-1)
            half8 af[4];
            af[0] = *(const half8*)&h0s[m * SROW + quad * 8];
            af[1] = *(const half8*)&h0s[m * SROW + 32 + quad * 8];
            af[2] = *(const half8*)&h1s[m * SROW + quad * 8];
            af[3] = *(const half8*)&h1s[m * SROW + 32 + quad * 8];
            float4v C[4];
            #pragma unroll
            for (int tau = 0; tau < 4; ++tau)
                C[tau] = (float4v){bias_a[tau], bias_a[tau], bias_a[tau], bias_a[tau]};
            #pragma unroll
            for (int kt = 0; kt < 4; ++kt)
                #pragma unroll
                for (int tau = 0; tau < 4; ++tau)
                    C[tau] = __builtin_amdgcn_mfma_f32_16x16x32_f16(af[kt], B1f[kt][tau], C[tau], 0, 0, 0);
            _Float16* o1 = &h1r[(t % 3) * SLOT];
            #pragma unroll
            for (int r = 0; r < 4; ++r) {
                const float ig = fast_sigmoid(C[0][r]);
                const float fg = fast_sigmoid(C[1][r]);
                const float gg = fast_tanh   (C[2][r]);
                const float og = fast_sigmoid(C[3][r]);
                const float c  = fg * c1s[r] + ig * gg;
                c1s[r] = c;
                o1[(quad * 4 + r) * SROW + jcol] = (_Float16)(og * fast_tanh(c));
            }
            __threadfence_block();
            if (lane == 0) atomicAdd(&ctr_h1, 1);
        }
    } else {
        // ================= layer-0 (+head) group =================
        float c0s[4] = {0.f, 0.f, 0.f, 0.f};
        for (int t = 0; t <= TT; ++t) {
            if (t < TT) {
                const bool enc = (t <= T_ENC);
                waitCtr(&ctr_h0, 4 * t);                          // own h0(t-1) done (skew)
                if (enc) waitCtr(&ctr_h1, 4 * (t - 2));           // anti-overrun (lead <= 2)
                else     waitCtr(&ctr_h1, 4 * t);                 // need h1(t-1)
                const _Float16* h0s = &h0r[((t + 3) & 3) * SLOT]; // slot of h0(t-1)
                half8 af[4];
                af[0] = *(const half8*)&h0s[m * SROW + quad * 8];
                af[1] = *(const half8*)&h0s[m * SROW + 32 + quad * 8];
                float4v C[4];
                const float* bs = enc ? bias_a : bias_b;
                #pragma unroll
                for (int tau = 0; tau < 4; ++tau)
                    C[tau] = (float4v){bs[tau], bs[tau], bs[tau], bs[tau]};
                #pragma unroll
                for (int kt = 0; kt < 2; ++kt)
                    #pragma unroll
                    for (int tau = 0; tau < 4; ++tau)
                        C[tau] = __builtin_amdgcn_mfma_f32_16x16x32_f16(af[kt], BWhh0[kt][tau], C[tau], 0, 0, 0);
                if (enc) {
                    const int tx = (t < T_ENC) ? t : T_ENC - 1;
                    half8 axf = (half8){0, 0, 0, 0, 0, 0, 0, 0};
                    if (quad == 0) {
                        const half4_t xv = *(const half4_t*)&xAll[(m * T_ENC + tx) * D_IN];
                        axf[0] = xv[0]; axf[1] = xv[1]; axf[2] = xv[2]; axf[3] = xv[3];
                    }
                    #pragma unroll
                    for (int tau = 0; tau < 4; ++tau)
                        C[tau] = __builtin_amdgcn_mfma_f32_16x16x32_f16(axf, Bx[tau], C[tau], 0, 0, 0);
                } else {
                    const _Float16* h1s = &h1r[((t + 2) % 3) * SLOT];   // h1(t-1)
                    af[2] = *(const half8*)&h1s[m * SROW + quad * 8];
                    af[3] = *(const half8*)&h1s[m * SROW + 32 + quad * 8];
                    #pragma unroll
                    for (int kt = 0; kt < 2; ++kt)
                        #pragma unroll
                        for (int tau = 0; tau < 4; ++tau)
                            C[tau] = __builtin_amdgcn_mfma_f32_16x16x32_f16(af[2 + kt], Wxf[kt][tau], C[tau], 0, 0, 0);
                    if (w4 == 0) {    // head: pred(t-129) = Wfc·h1(t-1)+bfc (off dataflow)
                        float4v Cp = (float4v){bfcv, bfcv, bfcv, bfcv};
                        Cp = __builtin_amdgcn_mfma_f32_16x16x32_f16(af[2], BfcF[0], Cp, 0, 0, 0);
                        Cp = __builtin_amdgcn_mfma_f32_16x16x32_f16(af[3], BfcF[1], Cp, 0, 0, 0);
                        if (n16 < 4) {
                            const int s = t - 129;
                            #pragma unroll
                            for (int r = 0; r < 4; ++r)
                                predsS[(quad * 4 + r) * (STEPS * D_IN) + s * D_IN + n16] = Cp[r];
                        }
                    }
                }
                _Float16* o0 = &h0r[(t & 3) * SLOT];
                #pragma unroll
                for (int r = 0; r < 4; ++r) {
                    const float ig = fast_sigmoid(C[0][r]);
                    const float fg = fast_sigmoid(C[1][r]);
                    const float gg = fast_tanh   (C[2][r]);
                    const float og = fast_sigmoid(C[3][r]);
                    const float c  = fg * c0s[r] + ig * gg;
                    c0s[r] = c;
                    o0[(quad * 4 + r) * SROW + jcol] = (_Float16)(og * fast_tanh(c));
                }
                __threadfence_block();
                if (lane == 0) atomicAdd(&ctr_h0, 1);
            } else if (w4 == 0) {
                // t == 188: final head, s = 59 on h1(187)
                waitCtr(&ctr_h1, 4 * TT);
                const _Float16* h1s = &h1r[((TT + 2) % 3) * SLOT];
                half8 a2 = *(const half8*)&h1s[m * SROW + quad * 8];
                half8 a3 = *(const half8*)&h1s[m * SROW + 32 + quad * 8];
                float4v Cp = (float4v){bfcv, bfcv, bfcv, bfcv};
                Cp = __builtin_amdgcn_mfma_f32_16x16x32_f16(a2, BfcF[0], Cp, 0, 0, 0);
                Cp = __builtin_amdgcn_mfma_f32_16x16x32_f16(a3, BfcF[1], Cp, 0, 0, 0);
                if (n16 < 4) {
                    #pragma unroll
                    for (int r = 0; r < 4; ++r)
                        predsS[(quad * 4 + r) * (STEPS * D_IN) + 59 * D_IN + n16] = Cp[r];
                }
            }
        }
    }

    __syncthreads();   // all preds written

    for (int j = tid; j < M * STEPS; j += NT) {
        const int elem = j / STEPS, r = j - elem * STEPS;
        ((float4v*)out)[(size_t)(m0 + elem) * STEPS + r] = ((const float4v*)predsS)[j];
    }
}

extern "C" void kernel_launch(void* const* d_in, const int* in_sizes, int n_in,
                              void* d_out, int out_size, void* d_ws, size_t ws_size,
                              hipStream_t stream) {
    const float* x    = (const float*)d_in[0];
    const float* Wih0 = (const float*)d_in[1];
    const float* Whh0 = (const float*)d_in[2];
    const float* bih0 = (const float*)d_in[3];
    const float* bhh0 = (const float*)d_in[4];
    const float* Wih1 = (const float*)d_in[5];
    const float* Whh1 = (const float*)d_in[6];
    const float* bih1 = (const float*)d_in[7];
    const float* bhh1 = (const float*)d_in[8];
    const float* Wfc  = (const float*)d_in[9];
    const float* bfc  = (const float*)d_in[10];
    float* out = (float*)d_out;

    dim3 grid(4096 / M);   // 256 blocks, one per CU
    dim3 block(NT);        // 8 waves: grp0 = layer1, grp1 = layer0+head
    lstm_ar_kernel<<<grid, block, 0, stream>>>(
        x, Wih0, Whh0, bih0, bhh0, Wih1, Whh1, bih1, bhh1, Wfc, bfc, out);
}